// Round 1
// baseline (372.710 us; speedup 1.0000x reference)
//
#include <hip/hip_runtime.h>
#include <math.h>

#define BATCH 16
#define LSEQ  4096
#define HDIM  1024
// 1/sqrt(2*1024)
#define INVSCALE 0.022097086912079608f

__device__ __forceinline__ void upd(float4& a, const float4& x, float corr, float w) {
    a.x = a.x * corr + w * x.x;
    a.y = a.y * corr + w * x.y;
    a.z = a.z * corr + w * x.z;
    a.w = a.w * corr + w * x.w;
}

// Pass 1: one block per (batch b, chunk c). 4 waves/block; each wave processes
// rows_per_wave full rows of inputs[b, l, :] with online softmax, accumulating
// ctx[h] in registers (16 floats/lane). Block-combine via LDS, write one
// partial (1024-float ctx, m, s) per block to workspace.
__global__ __launch_bounds__(256) void attn_pass1(
    const float* __restrict__ inputs,
    const float* __restrict__ query,
    float* __restrict__ ctx_part,
    float* __restrict__ m_part,
    float* __restrict__ s_part,
    int C, int rows_per_wave)
{
    const int blk  = blockIdx.x;
    const int b    = blk / C;
    const int c    = blk - b * C;
    const int tid  = threadIdx.x;
    const int wave = tid >> 6;   // 0..3
    const int lane = tid & 63;   // wave64

    // Preload query fragment: lane owns h = {4*lane..+3, +256, +512, +768}
    const float4* q4 = reinterpret_cast<const float4*>(query + (size_t)b * HDIM);
    const float4 q0 = q4[lane];
    const float4 q1 = q4[lane + 64];
    const float4 q2 = q4[lane + 128];
    const float4 q3 = q4[lane + 192];

    const int rows_per_block = rows_per_wave << 2;
    const int l0 = c * rows_per_block + wave * rows_per_wave;
    const float4* in4 = reinterpret_cast<const float4*>(inputs)
                      + ((size_t)b * LSEQ + l0) * (HDIM / 4);

    float m = -3.0e38f;
    float s = 0.0f;
    float4 a0 = make_float4(0.f, 0.f, 0.f, 0.f);
    float4 a1 = a0, a2 = a0, a3 = a0;

    for (int r = 0; r < rows_per_wave; ++r) {
        const float4* row = in4 + (size_t)r * (HDIM / 4);
        const float4 x0 = row[lane];
        const float4 x1 = row[lane + 64];
        const float4 x2 = row[lane + 128];
        const float4 x3 = row[lane + 192];

        // per-lane partial dot (16 elements)
        float p;
        p  = x0.x * q0.x + x0.y * q0.y + x0.z * q0.z + x0.w * q0.w;
        p += x1.x * q1.x + x1.y * q1.y + x1.z * q1.z + x1.w * q1.w;
        p += x2.x * q2.x + x2.y * q2.y + x2.z * q2.z + x2.w * q2.w;
        p += x3.x * q3.x + x3.y * q3.y + x3.z * q3.z + x3.w * q3.w;

        // wave-wide reduce (64 lanes)
        #pragma unroll
        for (int off = 32; off; off >>= 1) p += __shfl_xor(p, off);

        const float sim = p * INVSCALE;

        // branchless online softmax update (wave-uniform values)
        const float mn   = fmaxf(m, sim);
        const float corr = __expf(m - mn);
        const float w    = __expf(sim - mn);
        s = s * corr + w;
        m = mn;
        upd(a0, x0, corr, w);
        upd(a1, x1, corr, w);
        upd(a2, x2, corr, w);
        upd(a3, x3, corr, w);
    }

    // ---- combine the 4 waves of this block via LDS ----
    __shared__ float red[4][HDIM];
    __shared__ float mred[4], sred[4];
    {
        float4* dst = reinterpret_cast<float4*>(&red[wave][0]);
        dst[lane]       = a0;
        dst[lane + 64]  = a1;
        dst[lane + 128] = a2;
        dst[lane + 192] = a3;
        if (lane == 0) { mred[wave] = m; sred[wave] = s; }
    }
    __syncthreads();

    const float M  = fmaxf(fmaxf(mred[0], mred[1]), fmaxf(mred[2], mred[3]));
    const float f0 = __expf(mred[0] - M);
    const float f1 = __expf(mred[1] - M);
    const float f2 = __expf(mred[2] - M);
    const float f3 = __expf(mred[3] - M);
    const float S  = sred[0] * f0 + sred[1] * f1 + sred[2] * f2 + sred[3] * f3;

    // thread tid combines float4 index tid (256 threads x 4 floats = 1024)
    const float4 v0 = reinterpret_cast<const float4*>(&red[0][0])[tid];
    const float4 v1 = reinterpret_cast<const float4*>(&red[1][0])[tid];
    const float4 v2 = reinterpret_cast<const float4*>(&red[2][0])[tid];
    const float4 v3 = reinterpret_cast<const float4*>(&red[3][0])[tid];
    float4 o;
    o.x = v0.x * f0 + v1.x * f1 + v2.x * f2 + v3.x * f3;
    o.y = v0.y * f0 + v1.y * f1 + v2.y * f2 + v3.y * f3;
    o.z = v0.z * f0 + v1.z * f1 + v2.z * f2 + v3.z * f3;
    o.w = v0.w * f0 + v1.w * f1 + v2.w * f2 + v3.w * f3;

    const size_t slot = (size_t)b * C + c;
    reinterpret_cast<float4*>(ctx_part + slot * HDIM)[tid] = o;
    if (tid == 0) { m_part[slot] = M; s_part[slot] = S; }
}

// Pass 2: one block per batch; merge the C chunk-partials with softmax
// rescaling and normalize. Thread tid owns float4 index tid of the output row.
__global__ __launch_bounds__(256) void attn_pass2(
    const float* __restrict__ ctx_part,
    const float* __restrict__ m_part,
    const float* __restrict__ s_part,
    float* __restrict__ out, int C)
{
    __shared__ float ms[256], ss[256];  // C <= 128 by construction
    const int b   = blockIdx.x;
    const int tid = threadIdx.x;
    if (tid < C) {
        ms[tid] = m_part[(size_t)b * C + tid];
        ss[tid] = s_part[(size_t)b * C + tid];
    }
    __syncthreads();

    float M = -3.0e38f;
    for (int c = 0; c < C; ++c) M = fmaxf(M, ms[c]);

    float S = 0.0f;
    float4 o = make_float4(0.f, 0.f, 0.f, 0.f);
    for (int c = 0; c < C; ++c) {
        const float f = __expf(ms[c] - M);
        S += ss[c] * f;
        const float4 v = reinterpret_cast<const float4*>(
            ctx_part + ((size_t)b * C + c) * HDIM)[tid];
        o.x += v.x * f;
        o.y += v.y * f;
        o.z += v.z * f;
        o.w += v.w * f;
    }
    const float inv = 1.0f / S;
    float4 r;
    r.x = o.x * inv; r.y = o.y * inv; r.z = o.z * inv; r.w = o.w * inv;
    reinterpret_cast<float4*>(out + (size_t)b * HDIM)[tid] = r;
}

extern "C" void kernel_launch(void* const* d_in, const int* in_sizes, int n_in,
                              void* d_out, int out_size, void* d_ws, size_t ws_size,
                              hipStream_t stream) {
    const float* inputs = (const float*)d_in[0];   // [16, 4096, 1024] fp32
    const float* query  = (const float*)d_in[1];   // [16, 1024] fp32
    float* out = (float*)d_out;                    // [16, 1024] fp32

    // Pick chunks/batch C (power of 2) so partials fit the workspace.
    int C = 128;
    while (C > 1) {
        size_t need = (size_t)BATCH * C * (HDIM + 2) * sizeof(float);
        if (need <= ws_size) break;
        C >>= 1;
    }
    const int rows_per_wave = LSEQ / (C * 4);  // exact for C power-of-2 <= 1024

    float* ctx_part = (float*)d_ws;                          // [B][C][HDIM]
    float* m_part   = ctx_part + (size_t)BATCH * C * HDIM;   // [B][C]
    float* s_part   = m_part + (size_t)BATCH * C;            // [B][C]

    attn_pass1<<<dim3(BATCH * C), dim3(256), 0, stream>>>(
        inputs, query, ctx_part, m_part, s_part, C, rows_per_wave);
    attn_pass2<<<dim3(BATCH), dim3(256), 0, stream>>>(
        ctx_part, m_part, s_part, out, C);
}

// Round 3
// 370.803 us; speedup vs baseline: 1.0051x; 1.0051x over previous
//
#include <hip/hip_runtime.h>
#include <math.h>

#define BATCH 16
#define LSEQ  4096
#define HDIM  1024
// 1/sqrt(2*1024)
#define INVSCALE 0.022097086912079608f

__device__ __forceinline__ float dot16(const float4& x0, const float4& x1,
                                       const float4& x2, const float4& x3,
                                       const float4& q0, const float4& q1,
                                       const float4& q2, const float4& q3) {
    float p;
    p  = x0.x * q0.x + x0.y * q0.y + x0.z * q0.z + x0.w * q0.w;
    p += x1.x * q1.x + x1.y * q1.y + x1.z * q1.z + x1.w * q1.w;
    p += x2.x * q2.x + x2.y * q2.y + x2.z * q2.z + x2.w * q2.w;
    p += x3.x * q3.x + x3.y * q3.y + x3.z * q3.z + x3.w * q3.w;
    return p;
}

__device__ __forceinline__ void upd2(float4& a, const float4& x, const float4& y,
                                     float corr, float w0, float w1) {
    a.x = a.x * corr + w0 * x.x + w1 * y.x;
    a.y = a.y * corr + w0 * x.y + w1 * y.y;
    a.z = a.z * corr + w0 * x.z + w1 * y.z;
    a.w = a.w * corr + w0 * x.w + w1 * y.w;
}

// Pass 1: one block per (batch b, chunk c). 4 waves/block; each wave processes
// rows_per_wave rows (in PAIRS for ILP) with online softmax, accumulating
// ctx[h] in registers (16 floats/lane). Block-combine via LDS, one partial
// (1024-float ctx, m, s) per block to workspace.
__global__ __launch_bounds__(256) void attn_pass1(
    const float* __restrict__ inputs,
    const float* __restrict__ query,
    float* __restrict__ ctx_part,
    float* __restrict__ m_part,
    float* __restrict__ s_part,
    int C, int rows_per_wave)
{
    const int blk  = blockIdx.x;
    const int b    = blk / C;
    const int c    = blk - b * C;
    const int tid  = threadIdx.x;
    const int wave = tid >> 6;   // 0..3
    const int lane = tid & 63;   // wave64

    // Query fragment: lane owns h = {4*lane..+3, +256, +512, +768}
    const float4* q4 = reinterpret_cast<const float4*>(query + (size_t)b * HDIM);
    const float4 q0 = q4[lane];
    const float4 q1 = q4[lane + 64];
    const float4 q2 = q4[lane + 128];
    const float4 q3 = q4[lane + 192];

    const int rows_per_block = rows_per_wave << 2;
    const int l0 = c * rows_per_block + wave * rows_per_wave;
    const float4* in4 = reinterpret_cast<const float4*>(inputs)
                      + ((size_t)b * LSEQ + l0) * (HDIM / 4);

    float m = -3.0e38f;
    float s = 0.0f;
    float4 a0 = make_float4(0.f, 0.f, 0.f, 0.f);
    float4 a1 = a0, a2 = a0, a3 = a0;

    for (int r = 0; r < rows_per_wave; r += 2) {
        const float4* rowA = in4 + (size_t)r * (HDIM / 4);
        const float4* rowB = rowA + (HDIM / 4);
        // two independent row loads (32 KB/wave in flight)
        const float4 x0 = rowA[lane];
        const float4 x1 = rowA[lane + 64];
        const float4 x2 = rowA[lane + 128];
        const float4 x3 = rowA[lane + 192];
        const float4 y0 = rowB[lane];
        const float4 y1 = rowB[lane + 64];
        const float4 y2 = rowB[lane + 128];
        const float4 y3 = rowB[lane + 192];

        float pA = dot16(x0, x1, x2, x3, q0, q1, q2, q3);
        float pB = dot16(y0, y1, y2, y3, q0, q1, q2, q3);

        // interleaved butterflies (independent, pipeline)
        #pragma unroll
        for (int off = 32; off; off >>= 1) {
            pA += __shfl_xor(pA, off);
            pB += __shfl_xor(pB, off);
        }

        const float simA = pA * INVSCALE;
        const float simB = pB * INVSCALE;

        // combined online-softmax update for the pair (one rescale)
        const float mn   = fmaxf(m, fmaxf(simA, simB));
        const float corr = __expf(m - mn);
        const float w0   = __expf(simA - mn);
        const float w1   = __expf(simB - mn);
        s = s * corr + w0 + w1;
        m = mn;
        upd2(a0, x0, y0, corr, w0, w1);
        upd2(a1, x1, y1, corr, w0, w1);
        upd2(a2, x2, y2, corr, w0, w1);
        upd2(a3, x3, y3, corr, w0, w1);
    }

    // ---- combine the 4 waves of this block via LDS ----
    __shared__ float red[4][HDIM];
    __shared__ float mred[4], sred[4];
    {
        float4* dst = reinterpret_cast<float4*>(&red[wave][0]);
        dst[lane]       = a0;
        dst[lane + 64]  = a1;
        dst[lane + 128] = a2;
        dst[lane + 192] = a3;
        if (lane == 0) { mred[wave] = m; sred[wave] = s; }
    }
    __syncthreads();

    const float M  = fmaxf(fmaxf(mred[0], mred[1]), fmaxf(mred[2], mred[3]));
    const float f0 = __expf(mred[0] - M);
    const float f1 = __expf(mred[1] - M);
    const float f2 = __expf(mred[2] - M);
    const float f3 = __expf(mred[3] - M);
    const float S  = sred[0] * f0 + sred[1] * f1 + sred[2] * f2 + sred[3] * f3;

    const float4 v0 = reinterpret_cast<const float4*>(&red[0][0])[tid];
    const float4 v1 = reinterpret_cast<const float4*>(&red[1][0])[tid];
    const float4 v2 = reinterpret_cast<const float4*>(&red[2][0])[tid];
    const float4 v3 = reinterpret_cast<const float4*>(&red[3][0])[tid];
    float4 o;
    o.x = v0.x * f0 + v1.x * f1 + v2.x * f2 + v3.x * f3;
    o.y = v0.y * f0 + v1.y * f1 + v2.y * f2 + v3.y * f3;
    o.z = v0.z * f0 + v1.z * f1 + v2.z * f2 + v3.z * f3;
    o.w = v0.w * f0 + v1.w * f1 + v2.w * f2 + v3.w * f3;

    const size_t slot = (size_t)b * C + c;
    reinterpret_cast<float4*>(ctx_part + slot * HDIM)[tid] = o;
    if (tid == 0) { m_part[slot] = M; s_part[slot] = S; }
}

// Pass 2: one block per batch; merge the C chunk-partials and normalize.
__global__ __launch_bounds__(256) void attn_pass2(
    const float* __restrict__ ctx_part,
    const float* __restrict__ m_part,
    const float* __restrict__ s_part,
    float* __restrict__ out, int C)
{
    __shared__ float ms[256], ss[256];  // C <= 128 by construction
    const int b   = blockIdx.x;
    const int tid = threadIdx.x;
    if (tid < C) {
        ms[tid] = m_part[(size_t)b * C + tid];
        ss[tid] = s_part[(size_t)b * C + tid];
    }
    __syncthreads();

    float M = -3.0e38f;
    for (int c = 0; c < C; ++c) M = fmaxf(M, ms[c]);

    float S = 0.0f;
    float4 o = make_float4(0.f, 0.f, 0.f, 0.f);
    for (int c = 0; c < C; ++c) {
        const float f = __expf(ms[c] - M);
        S += ss[c] * f;
        const float4 v = reinterpret_cast<const float4*>(
            ctx_part + ((size_t)b * C + c) * HDIM)[tid];
        o.x += v.x * f;
        o.y += v.y * f;
        o.z += v.z * f;
        o.w += v.w * f;
    }
    const float inv = 1.0f / S;
    float4 r;
    r.x = o.x * inv; r.y = o.y * inv; r.z = o.z * inv; r.w = o.w * inv;
    reinterpret_cast<float4*>(out + (size_t)b * HDIM)[tid] = r;
}

extern "C" void kernel_launch(void* const* d_in, const int* in_sizes, int n_in,
                              void* d_out, int out_size, void* d_ws, size_t ws_size,
                              hipStream_t stream) {
    const float* inputs = (const float*)d_in[0];   // [16, 4096, 1024] fp32
    const float* query  = (const float*)d_in[1];   // [16, 1024] fp32
    float* out = (float*)d_out;                    // [16, 1024] fp32

    // Chunks/batch C (power of 2) sized to the workspace.
    int C = 128;
    while (C > 1) {
        size_t need = (size_t)BATCH * C * (HDIM + 2) * sizeof(float);
        if (need <= ws_size) break;
        C >>= 1;
    }
    const int rows_per_wave = LSEQ / (C * 4);  // 8 at C=128 (even: pair loop ok)

    float* ctx_part = (float*)d_ws;                          // [B][C][HDIM]
    float* m_part   = ctx_part + (size_t)BATCH * C * HDIM;   // [B][C]
    float* s_part   = m_part + (size_t)BATCH * C;            // [B][C]

    attn_pass1<<<dim3(BATCH * C), dim3(256), 0, stream>>>(
        inputs, query, ctx_part, m_part, s_part, C, rows_per_wave);
    attn_pass2<<<dim3(BATCH), dim3(256), 0, stream>>>(
        ctx_part, m_part, s_part, out, C);
}